// Round 5
// baseline (477.616 us; speedup 1.0000x reference)
//
#include <hip/hip_runtime.h>

// GRU, H=3, input (T,B,3) fp32, hidden (1,B,3).
// 4 lanes per chain (lane j owns hidden unit j, lane 3 mirrors unit 2),
// 16 chains/wave64, 256 blocks -> 1 wave per CU. Wall time = T x carried
// dependency chain h(t)->h(t+1).
//
// R5: transcendental-free gates via Pade[4/4] of tanh:
//       tanh(y) ~ y*(945+105u+u^2)/(945+420u+15u^2), u=y^2, |y| clamped 3.5
//     sigma(x) = 0.5+0.5*tanh(x/2)  (the 1/2 folded into weights).
//     One serial v_rcp per gate instead of exp2+rcp; r's rcp merged into the
//     tanh argument (y_n = c + d*rcpD_r).
//     Lane-split x loads (lane loads its own element, DPP-shared) cut the
//     prefetch ring 24->8 VGPRs so the 8-step prefetch distance survives
//     register allocation (R4's sunk-load pathology).

#define PF 8

__device__ __forceinline__ float rcpf(float v) { return __builtin_amdgcn_rcpf(v); }

// Broadcast lane (quad_base + K) to all lanes of the quad via DPP quad_perm.
template <int CTRL>
__device__ __forceinline__ float quad_bcast(float v) {
    int i = __float_as_int(v);
    int r = __builtin_amdgcn_update_dpp(i, i, CTRL, 0xF, 0xF, true);
    return __int_as_float(r);
}

__device__ __forceinline__ float clamp35(float v) {
    return fminf(3.5f, fmaxf(-3.5f, v));
}

__global__ __launch_bounds__(64, 1)
void gru_seq_kernel(const float* __restrict__ x,    // (T,B,3)
                    const float* __restrict__ h0,   // (B,3)
                    const float* __restrict__ Wih,  // (9,3) row-major
                    const float* __restrict__ Whh,  // (9,3)
                    const float* __restrict__ bih,  // (9)
                    const float* __restrict__ bhh,  // (9)
                    float* __restrict__ out,        // (T,B,3) then (B,3)
                    int T, int B)
{
    const int lane  = threadIdx.x & 63;
    const int q     = lane & 3;
    const int j     = (q < 3) ? q : 2;           // lane 3 duplicates unit 2
    const int chain = blockIdx.x * 16 + (lane >> 2);
    if (chain >= B) return;

    // r,z rows pre-scaled by 0.5 (sigma(x)=0.5+0.5*tanh(x/2)); n row natural.
    const float whr0 = 0.5f * Whh[(0 + j) * 3 + 0], whr1 = 0.5f * Whh[(0 + j) * 3 + 1], whr2 = 0.5f * Whh[(0 + j) * 3 + 2];
    const float whz0 = 0.5f * Whh[(3 + j) * 3 + 0], whz1 = 0.5f * Whh[(3 + j) * 3 + 1], whz2 = 0.5f * Whh[(3 + j) * 3 + 2];
    const float whn0 =        Whh[(6 + j) * 3 + 0], whn1 =        Whh[(6 + j) * 3 + 1], whn2 =        Whh[(6 + j) * 3 + 2];
    const float wir0 = 0.5f * Wih[(0 + j) * 3 + 0], wir1 = 0.5f * Wih[(0 + j) * 3 + 1], wir2 = 0.5f * Wih[(0 + j) * 3 + 2];
    const float wiz0 = 0.5f * Wih[(3 + j) * 3 + 0], wiz1 = 0.5f * Wih[(3 + j) * 3 + 1], wiz2 = 0.5f * Wih[(3 + j) * 3 + 2];
    const float win0 =        Wih[(6 + j) * 3 + 0], win1 =        Wih[(6 + j) * 3 + 1], win2 =        Wih[(6 + j) * 3 + 2];
    const float br2  = 0.5f * (bih[0 + j] + bhh[0 + j]);
    const float bz2  = 0.5f * (bih[3 + j] + bhh[3 + j]);
    const float bni  = bih[6 + j];
    const float bnh  = bhh[6 + j];

    // Initial hidden state.
    const int cb = chain * 3;
    float hv0 = h0[cb + 0];
    float hv1 = h0[cb + 1];
    float hv2 = h0[cb + 2];
    float myh = (j == 0) ? hv0 : ((j == 1) ? hv1 : hv2);

    const int stride   = B * 3;
    const int tmax_off = cb + j + (T - 1) * stride;  // clamp for tail prefetch

    // Lane-split x ring: slot u holds THIS lane's element (index j) of x[t]
    // for the next t with t%8==u. 8 VGPRs total.
    float xb[PF];

    // ---- Prologue ----
    // gp for step 0 from x[0]:
    float x0v = x[cb + 0], x1v = x[cb + 1], x2v = x[cb + 2];   // cold scalar loads
    float gpr = fmaf(wir0, x0v, fmaf(wir1, x1v, fmaf(wir2, x2v, br2)));
    float gpz = fmaf(wiz0, x0v, fmaf(wiz1, x1v, fmaf(wiz2, x2v, bz2)));
    float gpn = fmaf(win0, x0v, fmaf(win1, x1v, fmaf(win2, x2v, bni)));
    // Ring: slot u <- x[u] for u=1..7, slot 0 <- x[8]. (lane-split element j)
#pragma unroll
    for (int u = 1; u < PF; ++u) {
        int tt = (u < T) ? u : (T - 1);
        xb[u] = x[cb + j + tt * stride];
    }
    { int tt = (PF < T) ? PF : (T - 1); xb[0] = x[cb + j + tt * stride]; }

    int o_off  = cb + j;                          // store offset for t=0
    int pf_off = cb + j + (PF + 1) * stride;      // next offset to load (t=9)

    // Carried-chain step. Consumes gpr/gpz/gpn (projections for this t).
    auto core = [&]() {
        // Gate pre-activations (r,z in half-scale domain).
        float yr  = fmaf(whr0, hv0, fmaf(whr1, hv1, fmaf(whr2, hv2, gpr)));
        float yz  = fmaf(whz0, hv0, fmaf(whz1, hv1, fmaf(whz2, hv2, gpz)));
        float anh = fmaf(whn0, hv0, fmaf(whn1, hv1, fmaf(whn2, hv2, bnh)));

        // r-gate rational: r = 0.5 + 0.5*yr*Nr/Dr  (merged below).
        yr = clamp35(yr);
        float ur = yr * yr;
        float Nr = fmaf(ur + 105.0f, ur, 945.0f);
        float Dr = fmaf(fmaf(15.0f, ur, 420.0f), ur, 945.0f);
        float Rr = rcpf(Dr);                     // serial trans #1
        // tanh argument: y = ani + r*anh = (gpn + 0.5*anh) + (0.5*anh*yr*Nr)*Rr
        float c  = fmaf(0.5f, anh, gpn);
        float d  = (0.5f * anh) * (yr * Nr);
        float yn = fmaf(d, Rr, c);

        // z-gate rational (off critical path: only needed at the final fma).
        yz = clamp35(yz);
        float uz = yz * yz;
        float Nz = fmaf(uz + 105.0f, uz, 945.0f);
        float Dz = fmaf(fmaf(15.0f, uz, 420.0f), uz, 945.0f);
        float z  = fmaf(yz * Nz, 0.5f * rcpf(Dz), 0.5f);

        // n = tanh(yn) rational.
        yn = clamp35(yn);
        float un = yn * yn;
        float Nn = fmaf(un + 105.0f, un, 945.0f);
        float Dn = fmaf(fmaf(15.0f, un, 420.0f), un, 945.0f);
        float n  = (yn * Nn) * rcpf(Dn);         // serial trans #2

        myh = fmaf(z, myh - n, n);               // (1-z)*n + z*h

        out[o_off] = myh; o_off += stride;       // off-path
        hv0 = quad_bcast<0x00>(myh);
        hv1 = quad_bcast<0x55>(myh);
        hv2 = quad_bcast<0xAA>(myh);
    };

    const int nb = T / PF;
    for (int kb = 0; kb < nb; ++kb) {
#pragma unroll
        for (int u = 0; u < PF; ++u) {
            core();
            // Projections for step t+1 from ring slot (u+1)&7 (loaded 8 steps
            // ago), shared across the quad via DPP; then reload the slot with
            // x[t+9]. All indices compile-time after unroll.
            float xv = xb[(u + 1) & (PF - 1)];
            float xx0 = quad_bcast<0x00>(xv);
            float xx1 = quad_bcast<0x55>(xv);
            float xx2 = quad_bcast<0xAA>(xv);
            gpr = fmaf(wir0, xx0, fmaf(wir1, xx1, fmaf(wir2, xx2, br2)));
            gpz = fmaf(wiz0, xx0, fmaf(wiz1, xx1, fmaf(wiz2, xx2, bz2)));
            gpn = fmaf(win0, xx0, fmaf(win1, xx1, fmaf(win2, xx2, bni)));
            int off = pf_off; if (off > tmax_off) off = tmax_off;
            xb[(u + 1) & (PF - 1)] = x[(size_t)off];
            pf_off += stride;
        }
    }
    // Remainder (T % PF): straight-line, off the fast path.
    for (int t = nb * PF; t < T; ++t) {
        // gp for this t was produced by the previous iteration; just run core.
        core();
        const float* p = x + (size_t)(cb + ((t + 1 < T) ? (t + 1) : (T - 1)) * stride);
        float xx0 = p[0], xx1 = p[1], xx2 = p[2];
        gpr = fmaf(wir0, xx0, fmaf(wir1, xx1, fmaf(wir2, xx2, br2)));
        gpz = fmaf(wiz0, xx0, fmaf(wiz1, xx1, fmaf(wiz2, xx2, bz2)));
        gpn = fmaf(win0, xx0, fmaf(win1, xx1, fmaf(win2, xx2, bni)));
    }

    // h_last tail: d_out = [output (T*B*3) | h_last (B*3)].
    out[o_off] = myh;
}

extern "C" void kernel_launch(void* const* d_in, const int* in_sizes, int n_in,
                              void* d_out, int out_size, void* d_ws, size_t ws_size,
                              hipStream_t stream) {
    const float* x   = (const float*)d_in[0];
    const float* h0  = (const float*)d_in[1];
    const float* Wih = (const float*)d_in[2];
    const float* Whh = (const float*)d_in[3];
    const float* bih = (const float*)d_in[4];
    const float* bhh = (const float*)d_in[5];
    float* out = (float*)d_out;

    const int B = in_sizes[1] / 3;              // hidden is (1,B,3)
    const int T = in_sizes[0] / in_sizes[1];    // input is (T,B,3)

    const int grid = (B + 15) / 16;             // 16 chains per 64-thread block
    gru_seq_kernel<<<grid, 64, 0, stream>>>(x, h0, Wih, Whh, bih, bhh, out, T, B);
}